// Round 2
// baseline (1154.015 us; speedup 1.0000x reference)
//
#include <hip/hip_runtime.h>
#include <cstdint>
#include <cstddef>

#define NEG_SLOPE 0.2f
#define HEADS 4
#define CH 64
#define HC 256   // HEADS*CH

__device__ __forceinline__ float leaky(float x) { return x > 0.f ? x : NEG_SLOPE * x; }

// ---------------- GEMM: C[M x 256] = A[M x K] * B[K x 256], fp32 ----------------
// 128x128 tile, BK=8, 256 threads, 8x8 microtile: 64 FMA : 4 ds_read_b128 per k.
#define GBM 128
#define GBN 128
#define GBK 8
__global__ void gemm128(const float* __restrict__ A, const float* __restrict__ B,
                        float* __restrict__ C, int M, int K) {
    __shared__ float As[GBK][GBM];
    __shared__ float Bs[GBK][GBN];
    const int bm = blockIdx.x * GBM;
    const int bn = blockIdx.y * GBN;
    const int t  = threadIdx.x;          // 256 threads
    const int tx = t & 15;               // N-dir, 16 x 8 cols
    const int ty = t >> 4;               // M-dir, 16 x 8 rows

    const int ar = t >> 1, ac = (t & 1) * 4;     // A: 128 rows x 8 cols per step
    const int br = t >> 5, bc = (t & 31) * 4;    // B: 8 rows x 128 cols per step
    const int arow_g = bm + ar;

    float acc[8][8] = {};

    for (int k0 = 0; k0 < K; k0 += GBK) {
        float4 av;
        if (arow_g < M) av = *(const float4*)(A + (size_t)arow_g * K + k0 + ac);
        else            av = make_float4(0.f, 0.f, 0.f, 0.f);
        As[ac + 0][ar] = av.x;
        As[ac + 1][ar] = av.y;
        As[ac + 2][ar] = av.z;
        As[ac + 3][ar] = av.w;
        *(float4*)&Bs[br][bc] = *(const float4*)(B + (size_t)(k0 + br) * HC + bn + bc);
        __syncthreads();

#pragma unroll
        for (int kk = 0; kk < GBK; ++kk) {
            float a[8], b[8];
#pragma unroll
            for (int i = 0; i < 8; ++i) a[i] = As[kk][ty * 8 + i];
#pragma unroll
            for (int j = 0; j < 8; ++j) b[j] = Bs[kk][tx * 8 + j];
#pragma unroll
            for (int i = 0; i < 8; ++i)
#pragma unroll
                for (int j = 0; j < 8; ++j)
                    acc[i][j] += a[i] * b[j];
        }
        __syncthreads();
    }

#pragma unroll
    for (int i = 0; i < 8; ++i) {
        const int gr = bm + ty * 8 + i;
        if (gr < M) {
#pragma unroll
            for (int j = 0; j < 8; j += 4) {
                *(float4*)(C + (size_t)gr * HC + bn + tx * 8 + j) =
                    make_float4(acc[i][j], acc[i][j+1], acc[i][j+2], acc[i][j+3]);
            }
        }
    }
}

// ---- per-node: alpha_s, alpha_d, self-loop weight, denom init ----
__global__ void alpha_kernel(const float* __restrict__ h, const float* __restrict__ a_src,
                             const float* __restrict__ a_dst,
                             float* __restrict__ alps, float* __restrict__ alpd,
                             float* __restrict__ wself, float* __restrict__ denom, int Nn) {
    const int n = blockIdx.x;
    if (n >= Nn) return;
    const int t = threadIdx.x;           // 256 = 4 heads x 64 ch
    const int hd = t >> 6, lane = t & 63;
    const float v = h[(size_t)n * HC + t];
    float s = v * a_src[t];
    float d = v * a_dst[t];
#pragma unroll
    for (int off = 32; off; off >>= 1) {
        s += __shfl_down(s, off);
        d += __shfl_down(d, off);
    }
    if (lane == 0) {
        alps[n * HEADS + hd] = s;
        alpd[n * HEADS + hd] = d;
        const float w = __expf(leaky(s + d));   // no max subtraction (bounded logits)
        wself[n * HEADS + hd] = w;
        denom[n * HEADS + hd] = w;              // self-loop seed
    }
}

// ---- edge pass: denominator sum (no max pass) ----
__global__ void edge_sum_kernel(const int* __restrict__ ei,
                                const float* __restrict__ alps, const float* __restrict__ alpd,
                                float* __restrict__ denom, int E) {
    const int t = blockIdx.x * blockDim.x + threadIdx.x;
    if (t >= E * HEADS) return;
    const int e = t >> 2, hd = t & 3;
    const int src = ei[e], dst = ei[E + e];
    const float w = __expf(leaky(alps[src * HEADS + hd] + alpd[dst * HEADS + hd]));
    atomicAdd(&denom[dst * HEADS + hd], w);
}

// ---- per-node: invert denominator (in place) ----
__global__ void inv_kernel(float* __restrict__ denom, int Nn) {
    const int t = blockIdx.x * blockDim.x + threadIdx.x;
    if (t >= Nn * HEADS) return;
    denom[t] = 1.f / (denom[t] + 1e-16f);
}

// ---- edge aggregation: one wave per edge, lane = channel, heads folded ----
__global__ void edge_agg_kernel(const int* __restrict__ ei,
                                const float* __restrict__ alps, const float* __restrict__ alpd,
                                const float* __restrict__ dinv,
                                const float* __restrict__ hbuf, float* __restrict__ agg, int E) {
    const int wid = (blockIdx.x * blockDim.x + threadIdx.x) >> 6;
    const int lane = threadIdx.x & 63;
    if (wid >= E) return;
    const int src = ei[wid], dst = ei[E + wid];
    float acc = 0.f;
#pragma unroll
    for (int hd = 0; hd < HEADS; ++hd) {
        const float al = __expf(leaky(alps[src * HEADS + hd] + alpd[dst * HEADS + hd]))
                         * dinv[dst * HEADS + hd];
        acc += al * hbuf[(size_t)src * HC + hd * CH + lane];
    }
    atomicAdd(&agg[(size_t)dst * CH + lane], 0.25f * acc);
}

// ---- per-node finalize: self-loop msg, bias, optional ELU ----
__global__ void finalize_kernel(const float* __restrict__ hbuf,
                                const float* __restrict__ wself, const float* __restrict__ dinv,
                                const float* __restrict__ bias,
                                const float* __restrict__ agg, float* __restrict__ outp,
                                int Nn, int do_elu) {
    const size_t t = (size_t)blockIdx.x * blockDim.x + threadIdx.x;
    if (t >= (size_t)Nn * CH) return;
    const int n = (int)(t >> 6), c = (int)(t & 63);
    float acc = agg[t];
#pragma unroll
    for (int hd = 0; hd < HEADS; ++hd) {
        acc += 0.25f * wself[n * HEADS + hd] * dinv[n * HEADS + hd]
                     * hbuf[(size_t)n * HC + hd * CH + c];
    }
    float val = acc + bias[c];
    if (do_elu) val = val > 0.f ? val : expm1f(val);
    outp[t] = val;
}

// ------------------------------------------------------------------
extern "C" void kernel_launch(void* const* d_in, const int* in_sizes, int n_in,
                              void* d_out, int out_size, void* d_ws, size_t ws_size,
                              hipStream_t stream) {
    const float* x   = (const float*)d_in[0];
    const int*   ei  = (const int*)d_in[1];
    const float* W1  = (const float*)d_in[2];
    const float* a1s = (const float*)d_in[3];
    const float* a1d = (const float*)d_in[4];
    const float* b1  = (const float*)d_in[5];
    const float* W2  = (const float*)d_in[6];
    const float* a2s = (const float*)d_in[7];
    const float* a2d = (const float*)d_in[8];
    const float* b2  = (const float*)d_in[9];

    const int N = in_sizes[0] / HC;   // 50000
    const int E = in_sizes[1] / 2;    // 800000

    char* ws = (char*)d_ws;
    float* hbuf  = (float*)ws;                                     // N*256
    float* agg   = (float*)(ws + (size_t)N * HC * 4);              // N*64
    float* alps  = (float*)(ws + (size_t)N * HC * 4 + (size_t)N * CH * 4);
    float* alpd  = alps  + (size_t)N * HEADS;
    float* wself = alpd  + (size_t)N * HEADS;
    float* denom = wself + (size_t)N * HEADS;   // becomes inv_denom after inv_kernel
    float* outp  = (float*)d_out;

    const int edge_blk  = (E * HEADS + 255) / 256;
    const int node4_blk = (N * HEADS + 255) / 256;
    const int node64_blk = (N * CH + 255) / 256;
    const int agg_blk   = (E + 3) / 4;               // 4 waves/block, wave per edge
    const dim3 gemm_grid1((N + GBM - 1) / GBM, HC / GBN);

    // ---------------- layer 1 ----------------
    hipMemsetAsync(agg, 0, (size_t)N * CH * sizeof(float), stream);
    gemm128<<<gemm_grid1, 256, 0, stream>>>(x, W1, hbuf, N, 256);
    alpha_kernel<<<N, 256, 0, stream>>>(hbuf, a1s, a1d, alps, alpd, wself, denom, N);
    edge_sum_kernel<<<edge_blk, 256, 0, stream>>>(ei, alps, alpd, denom, E);
    inv_kernel<<<node4_blk, 256, 0, stream>>>(denom, N);
    edge_agg_kernel<<<agg_blk, 256, 0, stream>>>(ei, alps, alpd, denom, hbuf, agg, E);
    finalize_kernel<<<node64_blk, 256, 0, stream>>>(hbuf, wself, denom, b1,
                                                    agg, outp, N, 1);   // out1 -> d_out

    // ---------------- layer 2 ----------------
    gemm128<<<gemm_grid1, 256, 0, stream>>>(outp, W2, hbuf, N, CH);
    hipMemsetAsync(agg, 0, (size_t)N * CH * sizeof(float), stream);
    alpha_kernel<<<N, 256, 0, stream>>>(hbuf, a2s, a2d, alps, alpd, wself, denom, N);
    edge_sum_kernel<<<edge_blk, 256, 0, stream>>>(ei, alps, alpd, denom, E);
    inv_kernel<<<node4_blk, 256, 0, stream>>>(denom, N);
    edge_agg_kernel<<<agg_blk, 256, 0, stream>>>(ei, alps, alpd, denom, hbuf, agg, E);
    finalize_kernel<<<node64_blk, 256, 0, stream>>>(hbuf, wself, denom, b2,
                                                    agg, outp, N, 0);
}

// Round 3
// 705.609 us; speedup vs baseline: 1.6355x; 1.6355x over previous
//
#include <hip/hip_runtime.h>
#include <cstdint>
#include <cstddef>

#define NEG_SLOPE 0.2f
#define HEADS 4
#define CH 64
#define HC 256   // HEADS*CH

__device__ __forceinline__ float leaky(float x) { return x > 0.f ? x : NEG_SLOPE * x; }

// ---------------- GEMM: C[M x 256] = A[M x K] * B[K x 256], fp32 ----------------
// 128x128 tile, BK=8, 256 threads, 8x8 microtile.
// __launch_bounds__(256,2): without it hipcc compiles for 1024-thread blocks and
// caps VGPRs at 64 -> acc[8][8] spills to scratch (round-2: 2 GB HBM/dispatch, 9% VALU).
#define GBM 128
#define GBN 128
#define GBK 8
__global__ __launch_bounds__(256, 2)
void gemm128(const float* __restrict__ A, const float* __restrict__ B,
             float* __restrict__ C, int M, int K) {
    __shared__ float As[GBK][GBM];
    __shared__ float Bs[GBK][GBN];
    const int bm = blockIdx.x * GBM;
    const int bn = blockIdx.y * GBN;
    const int t  = threadIdx.x;          // 256 threads
    const int tx = t & 15;               // N-dir, 16 x 8 cols
    const int ty = t >> 4;               // M-dir, 16 x 8 rows

    const int ar = t >> 1, ac = (t & 1) * 4;     // A: 128 rows x 8 cols per step
    const int br = t >> 5, bc = (t & 31) * 4;    // B: 8 rows x 128 cols per step
    const int arow_g = bm + ar;

    float acc[8][8] = {};

    for (int k0 = 0; k0 < K; k0 += GBK) {
        float4 av;
        if (arow_g < M) av = *(const float4*)(A + (size_t)arow_g * K + k0 + ac);
        else            av = make_float4(0.f, 0.f, 0.f, 0.f);
        As[ac + 0][ar] = av.x;
        As[ac + 1][ar] = av.y;
        As[ac + 2][ar] = av.z;
        As[ac + 3][ar] = av.w;
        *(float4*)&Bs[br][bc] = *(const float4*)(B + (size_t)(k0 + br) * HC + bn + bc);
        __syncthreads();

#pragma unroll
        for (int kk = 0; kk < GBK; ++kk) {
            // ds_read_b128 x4 (conflict-free) instead of 16 scalar reads
            const float4 a0 = *(const float4*)&As[kk][ty * 8];
            const float4 a1 = *(const float4*)&As[kk][ty * 8 + 4];
            const float4 b0 = *(const float4*)&Bs[kk][tx * 8];
            const float4 b1 = *(const float4*)&Bs[kk][tx * 8 + 4];
            const float a[8] = {a0.x, a0.y, a0.z, a0.w, a1.x, a1.y, a1.z, a1.w};
            const float b[8] = {b0.x, b0.y, b0.z, b0.w, b1.x, b1.y, b1.z, b1.w};
#pragma unroll
            for (int i = 0; i < 8; ++i)
#pragma unroll
                for (int j = 0; j < 8; ++j)
                    acc[i][j] += a[i] * b[j];
        }
        __syncthreads();
    }

#pragma unroll
    for (int i = 0; i < 8; ++i) {
        const int gr = bm + ty * 8 + i;
        if (gr < M) {
#pragma unroll
            for (int j = 0; j < 8; j += 4) {
                *(float4*)(C + (size_t)gr * HC + bn + tx * 8 + j) =
                    make_float4(acc[i][j], acc[i][j+1], acc[i][j+2], acc[i][j+3]);
            }
        }
    }
}

// ---- per-node: alpha_s, alpha_d, self-loop weight, denom init ----
__global__ void alpha_kernel(const float* __restrict__ h, const float* __restrict__ a_src,
                             const float* __restrict__ a_dst,
                             float* __restrict__ alps, float* __restrict__ alpd,
                             float* __restrict__ wself, float* __restrict__ denom, int Nn) {
    const int n = blockIdx.x;
    if (n >= Nn) return;
    const int t = threadIdx.x;           // 256 = 4 heads x 64 ch
    const int hd = t >> 6, lane = t & 63;
    const float v = h[(size_t)n * HC + t];
    float s = v * a_src[t];
    float d = v * a_dst[t];
#pragma unroll
    for (int off = 32; off; off >>= 1) {
        s += __shfl_down(s, off);
        d += __shfl_down(d, off);
    }
    if (lane == 0) {
        alps[n * HEADS + hd] = s;
        alpd[n * HEADS + hd] = d;
        const float w = __expf(leaky(s + d));   // no max subtraction (bounded logits)
        wself[n * HEADS + hd] = w;
        denom[n * HEADS + hd] = w;              // self-loop seed
    }
}

// ---- edge pass: denominator sum (no max pass) ----
__global__ void edge_sum_kernel(const int* __restrict__ ei,
                                const float* __restrict__ alps, const float* __restrict__ alpd,
                                float* __restrict__ denom, int E) {
    const int t = blockIdx.x * blockDim.x + threadIdx.x;
    if (t >= E * HEADS) return;
    const int e = t >> 2, hd = t & 3;
    const int src = ei[e], dst = ei[E + e];
    const float w = __expf(leaky(alps[src * HEADS + hd] + alpd[dst * HEADS + hd]));
    atomicAdd(&denom[dst * HEADS + hd], w);
}

// ---- per-node: invert denominator (in place) ----
__global__ void inv_kernel(float* __restrict__ denom, int Nn) {
    const int t = blockIdx.x * blockDim.x + threadIdx.x;
    if (t >= Nn * HEADS) return;
    denom[t] = 1.f / (denom[t] + 1e-16f);
}

// ---- edge aggregation: one wave per edge, lane = channel, heads folded ----
__global__ void edge_agg_kernel(const int* __restrict__ ei,
                                const float* __restrict__ alps, const float* __restrict__ alpd,
                                const float* __restrict__ dinv,
                                const float* __restrict__ hbuf, float* __restrict__ agg, int E) {
    const int wid = (blockIdx.x * blockDim.x + threadIdx.x) >> 6;
    const int lane = threadIdx.x & 63;
    if (wid >= E) return;
    const int src = ei[wid], dst = ei[E + wid];
    float acc = 0.f;
#pragma unroll
    for (int hd = 0; hd < HEADS; ++hd) {
        const float al = __expf(leaky(alps[src * HEADS + hd] + alpd[dst * HEADS + hd]))
                         * dinv[dst * HEADS + hd];
        acc += al * hbuf[(size_t)src * HC + hd * CH + lane];
    }
    atomicAdd(&agg[(size_t)dst * CH + lane], 0.25f * acc);
}

// ---- per-node finalize: self-loop msg, bias, optional ELU ----
__global__ void finalize_kernel(const float* __restrict__ hbuf,
                                const float* __restrict__ wself, const float* __restrict__ dinv,
                                const float* __restrict__ bias,
                                const float* __restrict__ agg, float* __restrict__ outp,
                                int Nn, int do_elu) {
    const size_t t = (size_t)blockIdx.x * blockDim.x + threadIdx.x;
    if (t >= (size_t)Nn * CH) return;
    const int n = (int)(t >> 6), c = (int)(t & 63);
    float acc = agg[t];
#pragma unroll
    for (int hd = 0; hd < HEADS; ++hd) {
        acc += 0.25f * wself[n * HEADS + hd] * dinv[n * HEADS + hd]
                     * hbuf[(size_t)n * HC + hd * CH + c];
    }
    float val = acc + bias[c];
    if (do_elu) val = val > 0.f ? val : expm1f(val);
    outp[t] = val;
}

// ------------------------------------------------------------------
extern "C" void kernel_launch(void* const* d_in, const int* in_sizes, int n_in,
                              void* d_out, int out_size, void* d_ws, size_t ws_size,
                              hipStream_t stream) {
    const float* x   = (const float*)d_in[0];
    const int*   ei  = (const int*)d_in[1];
    const float* W1  = (const float*)d_in[2];
    const float* a1s = (const float*)d_in[3];
    const float* a1d = (const float*)d_in[4];
    const float* b1  = (const float*)d_in[5];
    const float* W2  = (const float*)d_in[6];
    const float* a2s = (const float*)d_in[7];
    const float* a2d = (const float*)d_in[8];
    const float* b2  = (const float*)d_in[9];

    const int N = in_sizes[0] / HC;   // 50000
    const int E = in_sizes[1] / 2;    // 800000

    char* ws = (char*)d_ws;
    float* hbuf  = (float*)ws;                                     // N*256
    float* agg   = (float*)(ws + (size_t)N * HC * 4);              // N*64
    float* alps  = (float*)(ws + (size_t)N * HC * 4 + (size_t)N * CH * 4);
    float* alpd  = alps  + (size_t)N * HEADS;
    float* wself = alpd  + (size_t)N * HEADS;
    float* denom = wself + (size_t)N * HEADS;   // becomes inv_denom after inv_kernel
    float* outp  = (float*)d_out;

    const int edge_blk  = (E * HEADS + 255) / 256;
    const int node4_blk = (N * HEADS + 255) / 256;
    const int node64_blk = (N * CH + 255) / 256;
    const int agg_blk   = (E + 3) / 4;               // 4 waves/block, wave per edge
    const dim3 gemm_grid1((N + GBM - 1) / GBM, HC / GBN);

    // ---------------- layer 1 ----------------
    hipMemsetAsync(agg, 0, (size_t)N * CH * sizeof(float), stream);
    gemm128<<<gemm_grid1, 256, 0, stream>>>(x, W1, hbuf, N, 256);
    alpha_kernel<<<N, 256, 0, stream>>>(hbuf, a1s, a1d, alps, alpd, wself, denom, N);
    edge_sum_kernel<<<edge_blk, 256, 0, stream>>>(ei, alps, alpd, denom, E);
    inv_kernel<<<node4_blk, 256, 0, stream>>>(denom, N);
    edge_agg_kernel<<<agg_blk, 256, 0, stream>>>(ei, alps, alpd, denom, hbuf, agg, E);
    finalize_kernel<<<node64_blk, 256, 0, stream>>>(hbuf, wself, denom, b1,
                                                    agg, outp, N, 1);   // out1 -> d_out

    // ---------------- layer 2 ----------------
    gemm128<<<gemm_grid1, 256, 0, stream>>>(outp, W2, hbuf, N, CH);
    hipMemsetAsync(agg, 0, (size_t)N * CH * sizeof(float), stream);
    alpha_kernel<<<N, 256, 0, stream>>>(hbuf, a2s, a2d, alps, alpd, wself, denom, N);
    edge_sum_kernel<<<edge_blk, 256, 0, stream>>>(ei, alps, alpd, denom, E);
    inv_kernel<<<node4_blk, 256, 0, stream>>>(denom, N);
    edge_agg_kernel<<<agg_blk, 256, 0, stream>>>(ei, alps, alpd, denom, hbuf, agg, E);
    finalize_kernel<<<node64_blk, 256, 0, stream>>>(hbuf, wself, denom, b2,
                                                    agg, outp, N, 0);
}

// Round 4
// 561.190 us; speedup vs baseline: 2.0564x; 1.2573x over previous
//
#include <hip/hip_runtime.h>
#include <cstdint>
#include <cstddef>

#define NEG_SLOPE 0.2f
#define HEADS 4
#define CH 64
#define HC 256   // HEADS*CH

__device__ __forceinline__ float leaky(float x) { return x > 0.f ? x : NEG_SLOPE * x; }

// ---------------- GEMM: C[M x 256] = A[M x K] * B[K x 256], fp32 ----------------
// 128x128 tile, BK=8, 256 threads, 8x8 microtile.
// __launch_bounds__(256,2): without it hipcc caps VGPRs at 64 -> acc spills (round-2).
#define GBM 128
#define GBN 128
#define GBK 8
__global__ __launch_bounds__(256, 2)
void gemm128(const float* __restrict__ A, const float* __restrict__ B,
             float* __restrict__ C, int M, int K) {
    __shared__ float As[GBK][GBM];
    __shared__ float Bs[GBK][GBN];
    const int bm = blockIdx.x * GBM;
    const int bn = blockIdx.y * GBN;
    const int t  = threadIdx.x;
    const int tx = t & 15;
    const int ty = t >> 4;

    const int ar = t >> 1, ac = (t & 1) * 4;
    const int br = t >> 5, bc = (t & 31) * 4;
    const int arow_g = bm + ar;

    float acc[8][8] = {};

    for (int k0 = 0; k0 < K; k0 += GBK) {
        float4 av;
        if (arow_g < M) av = *(const float4*)(A + (size_t)arow_g * K + k0 + ac);
        else            av = make_float4(0.f, 0.f, 0.f, 0.f);
        As[ac + 0][ar] = av.x;
        As[ac + 1][ar] = av.y;
        As[ac + 2][ar] = av.z;
        As[ac + 3][ar] = av.w;
        *(float4*)&Bs[br][bc] = *(const float4*)(B + (size_t)(k0 + br) * HC + bn + bc);
        __syncthreads();

#pragma unroll
        for (int kk = 0; kk < GBK; ++kk) {
            const float4 a0 = *(const float4*)&As[kk][ty * 8];
            const float4 a1 = *(const float4*)&As[kk][ty * 8 + 4];
            const float4 b0 = *(const float4*)&Bs[kk][tx * 8];
            const float4 b1 = *(const float4*)&Bs[kk][tx * 8 + 4];
            const float a[8] = {a0.x, a0.y, a0.z, a0.w, a1.x, a1.y, a1.z, a1.w};
            const float b[8] = {b0.x, b0.y, b0.z, b0.w, b1.x, b1.y, b1.z, b1.w};
#pragma unroll
            for (int i = 0; i < 8; ++i)
#pragma unroll
                for (int j = 0; j < 8; ++j)
                    acc[i][j] += a[i] * b[j];
        }
        __syncthreads();
    }

#pragma unroll
    for (int i = 0; i < 8; ++i) {
        const int gr = bm + ty * 8 + i;
        if (gr < M) {
#pragma unroll
            for (int j = 0; j < 8; j += 4) {
                *(float4*)(C + (size_t)gr * HC + bn + tx * 8 + j) =
                    make_float4(acc[i][j], acc[i][j+1], acc[i][j+2], acc[i][j+3]);
            }
        }
    }
}

// ---- per-node attention coefficients ----
__global__ void alpha_kernel(const float* __restrict__ h, const float* __restrict__ a_src,
                             const float* __restrict__ a_dst,
                             float* __restrict__ alps, float* __restrict__ alpd, int Nn) {
    const int n = blockIdx.x;
    if (n >= Nn) return;
    const int t = threadIdx.x;           // 256 = 4 heads x 64 ch
    const int hd = t >> 6, lane = t & 63;
    const float v = h[(size_t)n * HC + t];
    float s = v * a_src[t];
    float d = v * a_dst[t];
#pragma unroll
    for (int off = 32; off; off >>= 1) {
        s += __shfl_down(s, off);
        d += __shfl_down(d, off);
    }
    if (lane == 0) {
        alps[n * HEADS + hd] = s;
        alpd[n * HEADS + hd] = d;
    }
}

// ================= CSR construction (once per call; graph shared by both layers) =================
__global__ void hist_kernel(const int* __restrict__ ei, int* __restrict__ cnt, int E) {
    const int e = blockIdx.x * 256 + threadIdx.x;
    if (e >= E) return;
    atomicAdd(&cnt[ei[E + e]], 1);
}

__global__ void scan1_kernel(const int* __restrict__ cnt, int* __restrict__ excl,
                             int* __restrict__ bsum, int n) {
    __shared__ int tmp[256];
    const int tid = threadIdx.x;
    const int gid = blockIdx.x * 256 + tid;
    const int v = (gid < n) ? cnt[gid] : 0;
    tmp[tid] = v;
    __syncthreads();
    for (int off = 1; off < 256; off <<= 1) {
        const int t = (tid >= off) ? tmp[tid - off] : 0;
        __syncthreads();
        tmp[tid] += t;
        __syncthreads();
    }
    if (gid < n) excl[gid] = tmp[tid] - v;
    if (tid == 255) bsum[blockIdx.x] = tmp[255];
}

__global__ void scan2_kernel(int* __restrict__ bsum, int nb) {
    __shared__ int tmp[256];
    const int tid = threadIdx.x;
    const int v = (tid < nb) ? bsum[tid] : 0;
    tmp[tid] = v;
    __syncthreads();
    for (int off = 1; off < 256; off <<= 1) {
        const int t = (tid >= off) ? tmp[tid - off] : 0;
        __syncthreads();
        tmp[tid] += t;
        __syncthreads();
    }
    if (tid < nb) bsum[tid] = tmp[tid] - v;
}

__global__ void scan3_kernel(const int* __restrict__ excl, const int* __restrict__ bsum,
                             int* __restrict__ row_ptr, int* __restrict__ woff, int n) {
    const int gid = blockIdx.x * 256 + threadIdx.x;
    if (gid >= n) return;
    const int v = excl[gid] + bsum[blockIdx.x];
    row_ptr[gid] = v;
    woff[gid] = v;
}

__global__ void scatter_kernel(const int* __restrict__ ei, int* __restrict__ woff,
                               int* __restrict__ ssrc, int E) {
    const int e = blockIdx.x * 256 + threadIdx.x;
    if (e >= E) return;
    const int pos = atomicAdd(&woff[ei[E + e]], 1);
    ssrc[pos] = ei[e];
}

// ================= fused GAT aggregation: one wave per dst node =================
// lane = channel; 4 heads in registers. Single pass: accumulate unnormalized
// sum + denominator, normalize once at the end (softmax normalizer is
// per-dst-constant), fold head-mean + bias + ELU. No atomics anywhere.
__global__ __launch_bounds__(256)
void agg_csr_kernel(const int* __restrict__ row_ptr, const int* __restrict__ cnt,
                    const int* __restrict__ ssrc,
                    const float* __restrict__ alps, const float* __restrict__ alpd,
                    const float* __restrict__ hbuf, const float* __restrict__ bias,
                    float* __restrict__ outp, int Nn, int do_elu) {
    const int n = blockIdx.x * 4 + (threadIdx.x >> 6);
    const int c = threadIdx.x & 63;
    if (n >= Nn) return;

    const float4 aD = *(const float4*)&alpd[n * 4];
    const float4 aS0 = *(const float4*)&alps[n * 4];
    float acc[4], den[4];
    {   // self-loop
        const float w0 = __expf(leaky(aS0.x + aD.x));
        const float w1 = __expf(leaky(aS0.y + aD.y));
        const float w2 = __expf(leaky(aS0.z + aD.z));
        const float w3 = __expf(leaky(aS0.w + aD.w));
        const float* hr = hbuf + (size_t)n * HC;
        acc[0] = w0 * hr[c];       acc[1] = w1 * hr[64 + c];
        acc[2] = w2 * hr[128 + c]; acc[3] = w3 * hr[192 + c];
        den[0] = w0; den[1] = w1; den[2] = w2; den[3] = w3;
    }
    const int beg = row_ptr[n];
    const int end = beg + cnt[n];
    for (int e = beg; e < end; ++e) {
        const int src = ssrc[e];                          // wave-uniform broadcast
        const float4 aS = *(const float4*)&alps[src * 4]; // wave-uniform broadcast
        const float* hr = hbuf + (size_t)src * HC;
        const float w0 = __expf(leaky(aS.x + aD.x));
        const float w1 = __expf(leaky(aS.y + aD.y));
        const float w2 = __expf(leaky(aS.z + aD.z));
        const float w3 = __expf(leaky(aS.w + aD.w));
        acc[0] += w0 * hr[c];       acc[1] += w1 * hr[64 + c];
        acc[2] += w2 * hr[128 + c]; acc[3] += w3 * hr[192 + c];
        den[0] += w0; den[1] += w1; den[2] += w2; den[3] += w3;
    }
    float val = 0.25f * (acc[0] / den[0] + acc[1] / den[1] +
                         acc[2] / den[2] + acc[3] / den[3]) + bias[c];
    if (do_elu) val = val > 0.f ? val : expm1f(val);
    outp[(size_t)n * CH + c] = val;
}

// ------------------------------------------------------------------
extern "C" void kernel_launch(void* const* d_in, const int* in_sizes, int n_in,
                              void* d_out, int out_size, void* d_ws, size_t ws_size,
                              hipStream_t stream) {
    const float* x   = (const float*)d_in[0];
    const int*   ei  = (const int*)d_in[1];
    const float* W1  = (const float*)d_in[2];
    const float* a1s = (const float*)d_in[3];
    const float* a1d = (const float*)d_in[4];
    const float* b1  = (const float*)d_in[5];
    const float* W2  = (const float*)d_in[6];
    const float* a2s = (const float*)d_in[7];
    const float* a2d = (const float*)d_in[8];
    const float* b2  = (const float*)d_in[9];

    const int N = in_sizes[0] / HC;   // 50000
    const int E = in_sizes[1] / 2;    // 800000

    char* ws = (char*)d_ws;
    size_t off = 0;
    float* hbuf    = (float*)(ws + off); off += (size_t)N * HC * 4;
    float* alps    = (float*)(ws + off); off += (size_t)N * HEADS * 4;
    float* alpd    = (float*)(ws + off); off += (size_t)N * HEADS * 4;
    int*   cnt     = (int*)(ws + off);   off += (size_t)N * 4;
    int*   excl    = (int*)(ws + off);   off += (size_t)N * 4;
    int*   row_ptr = (int*)(ws + off);   off += (size_t)N * 4;
    int*   woff    = (int*)(ws + off);   off += (size_t)N * 4;
    int*   bsum    = (int*)(ws + off);   off += 256 * 4;
    int*   ssrc    = (int*)(ws + off);   off += (size_t)E * 4;
    float* outp    = (float*)d_out;

    const int eb   = (E + 255) / 256;
    const int nb   = (N + 255) / 256;        // 196 <= 256 (scan2 single-block limit)
    const int aggb = (N + 3) / 4;
    const dim3 gemm_grid((N + GBM - 1) / GBM, HC / GBN);

    // ---- CSR build (graph shared by both layers) ----
    hipMemsetAsync(cnt, 0, (size_t)N * 4, stream);
    hist_kernel<<<eb, 256, 0, stream>>>(ei, cnt, E);
    scan1_kernel<<<nb, 256, 0, stream>>>(cnt, excl, bsum, N);
    scan2_kernel<<<1, 256, 0, stream>>>(bsum, nb);
    scan3_kernel<<<nb, 256, 0, stream>>>(excl, bsum, row_ptr, woff, N);
    scatter_kernel<<<eb, 256, 0, stream>>>(ei, woff, ssrc, E);

    // ---------------- layer 1 ----------------
    gemm128<<<gemm_grid, 256, 0, stream>>>(x, W1, hbuf, N, 256);
    alpha_kernel<<<N, 256, 0, stream>>>(hbuf, a1s, a1d, alps, alpd, N);
    agg_csr_kernel<<<aggb, 256, 0, stream>>>(row_ptr, cnt, ssrc, alps, alpd,
                                             hbuf, b1, outp, N, 1);

    // ---------------- layer 2 ----------------
    gemm128<<<gemm_grid, 256, 0, stream>>>(outp, W2, hbuf, N, CH);
    alpha_kernel<<<N, 256, 0, stream>>>(hbuf, a2s, a2d, alps, alpd, N);
    agg_csr_kernel<<<aggb, 256, 0, stream>>>(row_ptr, cnt, ssrc, alps, alpd,
                                             hbuf, b2, outp, N, 0);
}

// Round 5
// 542.283 us; speedup vs baseline: 2.1281x; 1.0349x over previous
//
#include <hip/hip_runtime.h>
#include <cstdint>
#include <cstddef>

#define NEG_SLOPE 0.2f
#define HEADS 4
#define CH 64
#define HC 256   // HEADS*CH

__device__ __forceinline__ float leaky(float x) { return x > 0.f ? x : NEG_SLOPE * x; }

// ---------------- GEMM: C[M x 256] = A[M x K] * B[K x 256], fp32 ----------------
// 128x128 tile, BK=8, 256 threads, 8x8 microtile.
// __launch_bounds__(256,2): without it hipcc caps VGPRs at 64 -> acc spills (round-2).
#define GBM 128
#define GBN 128
#define GBK 8
__global__ __launch_bounds__(256, 2)
void gemm128(const float* __restrict__ A, const float* __restrict__ B,
             float* __restrict__ C, int M, int K) {
    __shared__ float As[GBK][GBM];
    __shared__ float Bs[GBK][GBN];
    const int bm = blockIdx.x * GBM;
    const int bn = blockIdx.y * GBN;
    const int t  = threadIdx.x;
    const int tx = t & 15;
    const int ty = t >> 4;

    const int ar = t >> 1, ac = (t & 1) * 4;
    const int br = t >> 5, bc = (t & 31) * 4;
    const int arow_g = bm + ar;

    float acc[8][8] = {};

    for (int k0 = 0; k0 < K; k0 += GBK) {
        float4 av;
        if (arow_g < M) av = *(const float4*)(A + (size_t)arow_g * K + k0 + ac);
        else            av = make_float4(0.f, 0.f, 0.f, 0.f);
        As[ac + 0][ar] = av.x;
        As[ac + 1][ar] = av.y;
        As[ac + 2][ar] = av.z;
        As[ac + 3][ar] = av.w;
        *(float4*)&Bs[br][bc] = *(const float4*)(B + (size_t)(k0 + br) * HC + bn + bc);
        __syncthreads();

#pragma unroll
        for (int kk = 0; kk < GBK; ++kk) {
            const float4 a0 = *(const float4*)&As[kk][ty * 8];
            const float4 a1 = *(const float4*)&As[kk][ty * 8 + 4];
            const float4 b0 = *(const float4*)&Bs[kk][tx * 8];
            const float4 b1 = *(const float4*)&Bs[kk][tx * 8 + 4];
            const float a[8] = {a0.x, a0.y, a0.z, a0.w, a1.x, a1.y, a1.z, a1.w};
            const float b[8] = {b0.x, b0.y, b0.z, b0.w, b1.x, b1.y, b1.z, b1.w};
#pragma unroll
            for (int i = 0; i < 8; ++i)
#pragma unroll
                for (int j = 0; j < 8; ++j)
                    acc[i][j] += a[i] * b[j];
        }
        __syncthreads();
    }

#pragma unroll
    for (int i = 0; i < 8; ++i) {
        const int gr = bm + ty * 8 + i;
        if (gr < M) {
#pragma unroll
            for (int j = 0; j < 8; j += 4) {
                *(float4*)(C + (size_t)gr * HC + bn + tx * 8 + j) =
                    make_float4(acc[i][j], acc[i][j+1], acc[i][j+2], acc[i][j+3]);
            }
        }
    }
}

// ---- per-node attention coefficients ----
__global__ void alpha_kernel(const float* __restrict__ h, const float* __restrict__ a_src,
                             const float* __restrict__ a_dst,
                             float* __restrict__ alps, float* __restrict__ alpd, int Nn) {
    const int n = blockIdx.x;
    if (n >= Nn) return;
    const int t = threadIdx.x;           // 256 = 4 heads x 64 ch
    const int hd = t >> 6, lane = t & 63;
    const float v = h[(size_t)n * HC + t];
    float s = v * a_src[t];
    float d = v * a_dst[t];
#pragma unroll
    for (int off = 32; off; off >>= 1) {
        s += __shfl_down(s, off);
        d += __shfl_down(d, off);
    }
    if (lane == 0) {
        alps[n * HEADS + hd] = s;
        alpd[n * HEADS + hd] = d;
    }
}

// ================= CSR construction (once per call; graph shared by both layers) =================
__global__ void hist_kernel(const int* __restrict__ ei, int* __restrict__ cnt, int E) {
    const int e = blockIdx.x * 256 + threadIdx.x;
    if (e >= E) return;
    atomicAdd(&cnt[ei[E + e]], 1);
}

__global__ void scan1_kernel(const int* __restrict__ cnt, int* __restrict__ excl,
                             int* __restrict__ bsum, int n) {
    __shared__ int tmp[256];
    const int tid = threadIdx.x;
    const int gid = blockIdx.x * 256 + tid;
    const int v = (gid < n) ? cnt[gid] : 0;
    tmp[tid] = v;
    __syncthreads();
    for (int off = 1; off < 256; off <<= 1) {
        const int t = (tid >= off) ? tmp[tid - off] : 0;
        __syncthreads();
        tmp[tid] += t;
        __syncthreads();
    }
    if (gid < n) excl[gid] = tmp[tid] - v;
    if (tid == 255) bsum[blockIdx.x] = tmp[255];
}

__global__ void scan2_kernel(int* __restrict__ bsum, int nb) {
    __shared__ int tmp[256];
    const int tid = threadIdx.x;
    const int v = (tid < nb) ? bsum[tid] : 0;
    tmp[tid] = v;
    __syncthreads();
    for (int off = 1; off < 256; off <<= 1) {
        const int t = (tid >= off) ? tmp[tid - off] : 0;
        __syncthreads();
        tmp[tid] += t;
        __syncthreads();
    }
    if (tid < nb) bsum[tid] = tmp[tid] - v;
}

__global__ void scan3_kernel(const int* __restrict__ excl, const int* __restrict__ bsum,
                             int* __restrict__ row_ptr, int* __restrict__ woff, int n) {
    const int gid = blockIdx.x * 256 + threadIdx.x;
    if (gid >= n) return;
    const int v = excl[gid] + bsum[blockIdx.x];
    row_ptr[gid] = v;
    woff[gid] = v;
}

__global__ void scatter_kernel(const int* __restrict__ ei, int* __restrict__ woff,
                               int* __restrict__ ssrc, int E) {
    const int e = blockIdx.x * 256 + threadIdx.x;
    if (e >= E) return;
    const int pos = atomicAdd(&woff[ei[E + e]], 1);
    ssrc[pos] = ei[e];
}

// ================= fused GAT aggregation: one wave per dst node =================
// lane = channel; 4 heads in registers. 4-edge software pipeline: issue the 4
// ssrc loads, then ALL 20 dependent loads (4x alpha float4 + 16 hbuf segments),
// then compute -> one dependence chain per 4 edges instead of per edge.
__global__ __launch_bounds__(256)
void agg_csr_kernel(const int* __restrict__ row_ptr, const int* __restrict__ cnt,
                    const int* __restrict__ ssrc,
                    const float* __restrict__ alps, const float* __restrict__ alpd,
                    const float* __restrict__ hbuf, const float* __restrict__ bias,
                    float* __restrict__ outp, int Nn, int do_elu) {
    const int n = blockIdx.x * 4 + (threadIdx.x >> 6);
    const int c = threadIdx.x & 63;
    if (n >= Nn) return;

    const float4 aD  = *(const float4*)&alpd[n * 4];
    const float4 aS0 = *(const float4*)&alps[n * 4];
    float acc[4], den[4];
    {   // self-loop
        const float w0 = __expf(leaky(aS0.x + aD.x));
        const float w1 = __expf(leaky(aS0.y + aD.y));
        const float w2 = __expf(leaky(aS0.z + aD.z));
        const float w3 = __expf(leaky(aS0.w + aD.w));
        const float* hr = hbuf + (size_t)n * HC;
        acc[0] = w0 * hr[c];       acc[1] = w1 * hr[64 + c];
        acc[2] = w2 * hr[128 + c]; acc[3] = w3 * hr[192 + c];
        den[0] = w0; den[1] = w1; den[2] = w2; den[3] = w3;
    }

    const int beg = row_ptr[n];
    const int end = beg + cnt[n];
    int e = beg;

    for (; e + 4 <= end; e += 4) {
        int s[4];
#pragma unroll
        for (int u = 0; u < 4; ++u) s[u] = ssrc[e + u];

        float4 aS[4];
#pragma unroll
        for (int u = 0; u < 4; ++u) aS[u] = *(const float4*)&alps[s[u] * 4];

        float hv[4][4];
#pragma unroll
        for (int u = 0; u < 4; ++u) {
            const float* hr = hbuf + (size_t)s[u] * HC;
            hv[u][0] = hr[c];
            hv[u][1] = hr[64 + c];
            hv[u][2] = hr[128 + c];
            hv[u][3] = hr[192 + c];
        }

#pragma unroll
        for (int u = 0; u < 4; ++u) {
            const float w0 = __expf(leaky(aS[u].x + aD.x));
            const float w1 = __expf(leaky(aS[u].y + aD.y));
            const float w2 = __expf(leaky(aS[u].z + aD.z));
            const float w3 = __expf(leaky(aS[u].w + aD.w));
            acc[0] += w0 * hv[u][0];  den[0] += w0;
            acc[1] += w1 * hv[u][1];  den[1] += w1;
            acc[2] += w2 * hv[u][2];  den[2] += w2;
            acc[3] += w3 * hv[u][3];  den[3] += w3;
        }
    }

    for (; e < end; ++e) {   // remainder (<=3 edges)
        const int src = ssrc[e];
        const float4 aS = *(const float4*)&alps[src * 4];
        const float* hr = hbuf + (size_t)src * HC;
        const float w0 = __expf(leaky(aS.x + aD.x));
        const float w1 = __expf(leaky(aS.y + aD.y));
        const float w2 = __expf(leaky(aS.z + aD.z));
        const float w3 = __expf(leaky(aS.w + aD.w));
        acc[0] += w0 * hr[c];        den[0] += w0;
        acc[1] += w1 * hr[64 + c];   den[1] += w1;
        acc[2] += w2 * hr[128 + c];  den[2] += w2;
        acc[3] += w3 * hr[192 + c];  den[3] += w3;
    }

    float val = 0.25f * (acc[0] / den[0] + acc[1] / den[1] +
                         acc[2] / den[2] + acc[3] / den[3]) + bias[c];
    if (do_elu) val = val > 0.f ? val : expm1f(val);
    outp[(size_t)n * CH + c] = val;
}

// ------------------------------------------------------------------
extern "C" void kernel_launch(void* const* d_in, const int* in_sizes, int n_in,
                              void* d_out, int out_size, void* d_ws, size_t ws_size,
                              hipStream_t stream) {
    const float* x   = (const float*)d_in[0];
    const int*   ei  = (const int*)d_in[1];
    const float* W1  = (const float*)d_in[2];
    const float* a1s = (const float*)d_in[3];
    const float* a1d = (const float*)d_in[4];
    const float* b1  = (const float*)d_in[5];
    const float* W2  = (const float*)d_in[6];
    const float* a2s = (const float*)d_in[7];
    const float* a2d = (const float*)d_in[8];
    const float* b2  = (const float*)d_in[9];

    const int N = in_sizes[0] / HC;   // 50000
    const int E = in_sizes[1] / 2;    // 800000

    char* ws = (char*)d_ws;
    size_t off = 0;
    float* hbuf    = (float*)(ws + off); off += (size_t)N * HC * 4;
    float* alps    = (float*)(ws + off); off += (size_t)N * HEADS * 4;
    float* alpd    = (float*)(ws + off); off += (size_t)N * HEADS * 4;
    int*   cnt     = (int*)(ws + off);   off += (size_t)N * 4;
    int*   excl    = (int*)(ws + off);   off += (size_t)N * 4;
    int*   row_ptr = (int*)(ws + off);   off += (size_t)N * 4;
    int*   woff    = (int*)(ws + off);   off += (size_t)N * 4;
    int*   bsum    = (int*)(ws + off);   off += 256 * 4;
    int*   ssrc    = (int*)(ws + off);   off += (size_t)E * 4;
    float* outp    = (float*)d_out;

    const int eb   = (E + 255) / 256;
    const int nb   = (N + 255) / 256;        // 196 <= 256 (scan2 single-block limit)
    const int aggb = (N + 3) / 4;
    const dim3 gemm_grid((N + GBM - 1) / GBM, HC / GBN);

    // ---- CSR build (graph shared by both layers) ----
    hipMemsetAsync(cnt, 0, (size_t)N * 4, stream);
    hist_kernel<<<eb, 256, 0, stream>>>(ei, cnt, E);
    scan1_kernel<<<nb, 256, 0, stream>>>(cnt, excl, bsum, N);
    scan2_kernel<<<1, 256, 0, stream>>>(bsum, nb);
    scan3_kernel<<<nb, 256, 0, stream>>>(excl, bsum, row_ptr, woff, N);
    scatter_kernel<<<eb, 256, 0, stream>>>(ei, woff, ssrc, E);

    // ---------------- layer 1 ----------------
    gemm128<<<gemm_grid, 256, 0, stream>>>(x, W1, hbuf, N, 256);
    alpha_kernel<<<N, 256, 0, stream>>>(hbuf, a1s, a1d, alps, alpd, N);
    agg_csr_kernel<<<aggb, 256, 0, stream>>>(row_ptr, cnt, ssrc, alps, alpd,
                                             hbuf, b1, outp, N, 1);

    // ---------------- layer 2 ----------------
    gemm128<<<gemm_grid, 256, 0, stream>>>(outp, W2, hbuf, N, CH);
    alpha_kernel<<<N, 256, 0, stream>>>(hbuf, a2s, a2d, alps, alpd, N);
    agg_csr_kernel<<<aggb, 256, 0, stream>>>(row_ptr, cnt, ssrc, alps, alpd,
                                             hbuf, b2, outp, N, 0);
}